// Round 14
// baseline (212.260 us; speedup 1.0000x reference)
//
#include <hip/hip_runtime.h>

#define NL 17
#define IGN (-100)
#define HD 384
#define NSEQ 1024
#define NT 65536
#define BIGI NT
#define TPB 256
#define NBLK (NT / TPB)        // 256
#define NS 24                  // 16-col slices
#define WPAD 392               // u16 row stride for bf16 W

typedef unsigned int u32;
typedef unsigned short u16;
typedef __attribute__((ext_vector_type(8))) short bf16x8;
typedef __attribute__((ext_vector_type(16))) float f32x16;

__device__ __forceinline__ u32 cvtpk(float lo, float hi) {
  u32 u;
  asm("v_cvt_pk_bf16_f32 %0, %1, %2" : "=v"(u) : "v"(lo), "v"(hi));
  return u;
}

struct WS {
  float ce_part[NBLK];
  float ctx_part[NBLK];
  int   ce_cnt[NBLK];
  int   ctx_cnt[NBLK];
  int   blk_a[NBLK][16];
  int   blk_p[NBLK][16];
  int   blk_c[NBLK][16];
  int   blk_d[NBLK];
};

// ---- main: register-streamed (no LDS staging, no barriers in stream) ----
__global__ __launch_bounds__(256, 2) void k_main(const float* __restrict__ emb,
                                                 const float* __restrict__ cw,
                                                 const float* __restrict__ cb,
                                                 const int* __restrict__ labels,
                                                 const int* __restrict__ mask,
                                                 WS* __restrict__ ws) {
  __shared__ u16   sWh[NL * WPAD];      // 13.3 KB W in bf16
  __shared__ float pcxA[4][64], pcxB[4][64];
  __shared__ float logit_s[TPB * 21];   // 21.5 KB
  __shared__ float sce[4], sctx[4];
  __shared__ int   svc[4], spc[4];
  __shared__ int   sla[16], slp[16], slc[16], sld;

  const int tid = threadIdx.x, lane = tid & 63, wid = tid >> 6;
  const int b = blockIdx.x;
  const int token = b * TPB + tid;

  // ---- W -> LDS as bf16 (once); scan init ----
  for (int i = tid; i < NL * (HD / 2); i += TPB) {
    int c = i / (HD / 2), p = i % (HD / 2);
    u32 pk = cvtpk(cw[c * HD + 2 * p], cw[c * HD + 2 * p + 1]);
    *(u32*)&sWh[c * WPAD + 2 * p] = pk;
  }
  if (tid < 16) { sla[tid] = BIGI; slp[tid] = BIGI; slc[tid] = 0; }
  if (tid == 16) sld = BIGI;
  __syncthreads();

  // ---- per-lane streaming geometry ----
  const int cls = lane & 31;
  const int kh  = lane >> 5;
  const int clsS = (cls < NL) ? cls : 0;
  const size_t rowA = (size_t)b * TPB + wid * 64 + (lane & 31);
  const float4* eA = (const float4*)emb + rowA * (HD / 4);
  const float4* eB = eA + 32 * (HD / 4);          // row +32
  const int co = 2 * kh;                          // f4 offset within slice

  f32x16 d0 = {0.f}, d1 = {0.f};
  float cxA = 0.f, cxB = 0.f;

  struct Slot { float4 a0, a1, b0, b1; };
  Slot S[3];

  auto LD = [&](int sl, int s) {
    S[sl].a0 = eA[4 * s + co];
    S[sl].a1 = eA[4 * s + co + 1];
    S[sl].b0 = eB[4 * s + co];
    S[sl].b1 = eB[4 * s + co + 1];
  };
  auto CP = [&](int sl, int s) {
    float4 A0 = S[sl].a0, A1 = S[sl].a1, B0 = S[sl].b0, B1 = S[sl].b1;
    // ctx partials: neighbor token = lane+1 within the 32-group
    // (lanes with (lane&31)==31 produce garbage here -> overridden in epilogue)
    float n, d;
    n = __shfl(A0.x, lane + 1); d = A0.x - n; cxA = fmaf(d, d, cxA);
    n = __shfl(A0.y, lane + 1); d = A0.y - n; cxA = fmaf(d, d, cxA);
    n = __shfl(A0.z, lane + 1); d = A0.z - n; cxA = fmaf(d, d, cxA);
    n = __shfl(A0.w, lane + 1); d = A0.w - n; cxA = fmaf(d, d, cxA);
    n = __shfl(A1.x, lane + 1); d = A1.x - n; cxA = fmaf(d, d, cxA);
    n = __shfl(A1.y, lane + 1); d = A1.y - n; cxA = fmaf(d, d, cxA);
    n = __shfl(A1.z, lane + 1); d = A1.z - n; cxA = fmaf(d, d, cxA);
    n = __shfl(A1.w, lane + 1); d = A1.w - n; cxA = fmaf(d, d, cxA);
    n = __shfl(B0.x, lane + 1); d = B0.x - n; cxB = fmaf(d, d, cxB);
    n = __shfl(B0.y, lane + 1); d = B0.y - n; cxB = fmaf(d, d, cxB);
    n = __shfl(B0.z, lane + 1); d = B0.z - n; cxB = fmaf(d, d, cxB);
    n = __shfl(B0.w, lane + 1); d = B0.w - n; cxB = fmaf(d, d, cxB);
    n = __shfl(B1.x, lane + 1); d = B1.x - n; cxB = fmaf(d, d, cxB);
    n = __shfl(B1.y, lane + 1); d = B1.y - n; cxB = fmaf(d, d, cxB);
    n = __shfl(B1.z, lane + 1); d = B1.z - n; cxB = fmaf(d, d, cxB);
    n = __shfl(B1.w, lane + 1); d = B1.w - n; cxB = fmaf(d, d, cxB);
    // MFMA fragments
    union { u32 u[4]; bf16x8 v; } BA, BB;
    BA.u[0] = cvtpk(A0.x, A0.y); BA.u[1] = cvtpk(A0.z, A0.w);
    BA.u[2] = cvtpk(A1.x, A1.y); BA.u[3] = cvtpk(A1.z, A1.w);
    BB.u[0] = cvtpk(B0.x, B0.y); BB.u[1] = cvtpk(B0.z, B0.w);
    BB.u[2] = cvtpk(B1.x, B1.y); BB.u[3] = cvtpk(B1.z, B1.w);
    bf16x8 af;
    if (cls < NL) af = *(const bf16x8*)&sWh[clsS * WPAD + s * 16 + kh * 8];
    else { union { u32 u[4]; bf16x8 v; } Z; Z.u[0]=0; Z.u[1]=0; Z.u[2]=0; Z.u[3]=0; af = Z.v; }
    d0 = __builtin_amdgcn_mfma_f32_32x32x16_bf16(af, BA.v, d0, 0, 0, 0);
    d1 = __builtin_amdgcn_mfma_f32_32x32x16_bf16(af, BB.v, d1, 0, 0, 0);
  };

  LD(0, 0); LD(1, 1);
#pragma unroll
  for (int s = 0; s < NS; ++s) {           // fully unrolled: all slot indices fold
    if (s + 2 < NS) LD((s + 2) % 3, s + 2);
    CP(s % 3, s);
  }

  // ---- per-wave edge-pair SSDs via global reads (rows are cache-hot) ----
  const int base = b * TPB + wid * 64;
  float ssd31 = 0.f, ssd63 = 0.f;
  {
    const float* r0 = emb + (size_t)(base + 31) * HD;   // pair (base+31, base+32): never a seq end
    const float* r1 = r0 + HD;
    float a = 0.f;
#pragma unroll
    for (int j = 0; j < 6; ++j) { float dd = r0[lane + 64 * j] - r1[lane + 64 * j]; a = fmaf(dd, dd, a); }
#pragma unroll
    for (int off = 32; off; off >>= 1) a += __shfl_xor(a, off, 64);
    ssd31 = a;
  }
  if (((base + 64) & (NSEQ - 1)) != 0) {   // pair (base+63, base+64): guard seq end / OOB
    const float* r0 = emb + (size_t)(base + 63) * HD;
    const float* r1 = r0 + HD;
    float a = 0.f;
#pragma unroll
    for (int j = 0; j < 6; ++j) { float dd = r0[lane + 64 * j] - r1[lane + 64 * j]; a = fmaf(dd, dd, a); }
#pragma unroll
    for (int off = 32; off; off >>= 1) a += __shfl_xor(a, off, 64);
    ssd63 = a;
  }

  // ---- spill ctx partials + logits ----
  pcxA[wid][lane] = cxA;
  pcxB[wid][lane] = cxB;
#pragma unroll
  for (int r = 0; r < 16; ++r) {
    int row = (r & 3) + 8 * (r >> 2) + 4 * kh;   // class
    if (row < NL) {
      logit_s[(wid * 64 + (lane & 31)) * 21 + row] = d0[r];
      logit_s[(wid * 64 + 32 + (lane & 31)) * 21 + row] = d1[r];
    }
  }
  __syncthreads();

  // ---- fused label scan ----
  int lb = labels[token];
  int mk = mask[token];
  int lbm = (mk > 0) ? lb : IGN;
  if (lbm == 0) atomicMin(&sld, token);
  else if (lbm >= 1 && lbm < NL) { atomicMin(&sla[lbm - 1], token); atomicAdd(&slc[lbm - 1], 1); }
  __syncthreads();
  if (lbm >= 1 && lbm < NL && token > sla[lbm - 1]) atomicMin(&slp[lbm - 1], token);

  // ---- softmax + CE + ctx pair ----
  float lg[NL];
#pragma unroll
  for (int c = 0; c < NL; ++c) lg[c] = logit_s[tid * 21 + c] + cb[c];
  float m = lg[0];
#pragma unroll
  for (int c = 1; c < NL; ++c) m = fmaxf(m, lg[c]);
  float sx = 0.f;
#pragma unroll
  for (int c = 0; c < NL; ++c) sx += __expf(lg[c] - m);
  float lse = m + __logf(sx);
  int safe = (lb == IGN) ? 0 : lb;
  float ll = 0.f;
#pragma unroll
  for (int c = 0; c < NL; ++c) ll = (c == safe) ? lg[c] : ll;
  bool valid = (lb != IGN);
  float cev = valid ? (lse - ll) : 0.f;

  // per-token ctx SSD (edge tokens take the global-read value)
  const int r = lane;
  float cs = (r < 32) ? (pcxA[wid][r] + pcxA[wid][r + 32])
                      : (pcxB[wid][r - 32] + pcxB[wid][r]);
  if (r == 31) cs = ssd31;
  if (r == 63) cs = ssd63;

  bool inrange = ((token + 1) & (NSEQ - 1)) != 0;      // also guards token+1 < NT
  int nlb = inrange ? labels[token + 1] : IGN;
  bool pair = inrange && valid && (lb == nlb) && (lb > 0);
  float ctxv = pair ? cs * (1.0f / HD) : 0.f;

  unsigned long long bv = __ballot(valid);
  unsigned long long bp = __ballot(pair);
#pragma unroll
  for (int off = 32; off; off >>= 1) {
    cev  += __shfl_xor(cev, off, 64);
    ctxv += __shfl_xor(ctxv, off, 64);
  }
  if (lane == 0) { sce[wid] = cev; sctx[wid] = ctxv; svc[wid] = __popcll(bv); spc[wid] = __popcll(bp); }
  __syncthreads();
  if (tid < 16) {
    ws->blk_a[b][tid] = sla[tid];
    ws->blk_p[b][tid] = slp[tid];
    ws->blk_c[b][tid] = slc[tid];
  }
  if (tid == 16) ws->blk_d[b] = sld;
  if (tid == 0) {
    ws->ce_part[b]  = sce[0] + sce[1] + sce[2] + sce[3];
    ws->ce_cnt[b]   = svc[0] + svc[1] + svc[2] + svc[3];
    ws->ctx_part[b] = sctx[0] + sctx[1] + sctx[2] + sctx[3];
    ws->ctx_cnt[b]  = spc[0] + spc[1] + spc[2] + spc[3];
  }
}

// ---------------- finalize (r13 verbatim) ----------------
__global__ __launch_bounds__(256) void k_final(const float* __restrict__ emb,
                                               WS* __restrict__ ws,
                                               float* __restrict__ out) {
  __shared__ double rce[256], rctx[256];
  __shared__ int rvc[256], rpc[256], rd[256];
  __shared__ int M1[256], M2[256], CN[256];
  __shared__ int ga[16], gp[16], gc[16];
  __shared__ float qs[4]; __shared__ int qc[4];
  const int tid = threadIdx.x, lane = tid & 63, wid = tid >> 6;

  rce[tid]  = ws->ce_part[tid];
  rctx[tid] = ws->ctx_part[tid];
  rvc[tid]  = ws->ce_cnt[tid];
  rpc[tid]  = ws->ctx_cnt[tid];
  rd[tid]   = ws->blk_d[tid];

  {
    const int type = tid & 15, seg = tid >> 4;
    int m1 = BIGI, m2 = BIGI, cnt = 0;
#pragma unroll 4
    for (int k = 0; k < 16; ++k) {
      int bb = seg * 16 + k;
      int x = ws->blk_a[bb][type];
      if (x < m1) { m2 = m1; m1 = x; } else if (x < m2) { m2 = x; }
      int y = ws->blk_p[bb][type];
      if (y < m1) { m2 = m1; m1 = y; } else if (y < m2) { m2 = y; }
      cnt += ws->blk_c[bb][type];
    }
    M1[tid] = m1; M2[tid] = m2; CN[tid] = cnt;
  }
  __syncthreads();
  for (int s = 128; s > 0; s >>= 1) {
    if (tid < s) {
      rce[tid] += rce[tid + s]; rctx[tid] += rctx[tid + s];
      rvc[tid] += rvc[tid + s]; rpc[tid] += rpc[tid + s];
      rd[tid] = min(rd[tid], rd[tid + s]);
    }
    __syncthreads();
  }
  if (tid < 16) {
    int m1 = BIGI, m2 = BIGI, cnt = 0;
    for (int seg = 0; seg < 16; ++seg) {
      int a1 = M1[seg * 16 + tid], a2 = M2[seg * 16 + tid];
      int n1 = min(m1, a1);
      int n2 = min(max(m1, a1), min(m2, a2));
      m1 = n1; m2 = n2;
      cnt += CN[seg * 16 + tid];
    }
    ga[tid] = m1; gp[tid] = m2; gc[tid] = cnt;
  }
  __syncthreads();

  const int gd = rd[0];
  float qsum = 0.f; int qcnt = 0;
  for (int tt = 0; tt < 4; ++tt) {
    int t = wid * 4 + tt;
    int a = ga[t], p = gp[t], c = gc[t];
    int nmin = BIGI;
#pragma unroll
    for (int u = 0; u < 16; ++u) if (u != t) nmin = min(nmin, ga[u]);
    bool ok = (c >= 2) && (nmin < BIGI) && (gd < BIGI);
    if (ok) {
      const float* A  = emb + (size_t)min(a, NT - 1) * HD;
      const float* P  = emb + (size_t)min(p, NT - 1) * HD;
      const float* Ng = emb + (size_t)min(nmin, NT - 1) * HD;
      const float* D  = emb + (size_t)min(gd, NT - 1) * HD;
      float sap = 0.f, san = 0.f, sad = 0.f;
#pragma unroll
      for (int j = 0; j < 6; ++j) {
        int idx = lane + 64 * j;
        float av = A[idx];
        float d1 = av - P[idx] + 1e-6f;  sap = fmaf(d1, d1, sap);
        float d2 = av - Ng[idx] + 1e-6f; san = fmaf(d2, d2, san);
        float d3 = av - D[idx] + 1e-6f;  sad = fmaf(d3, d3, sad);
      }
#pragma unroll
      for (int off = 32; off; off >>= 1) {
        sap += __shfl_xor(sap, off, 64);
        san += __shfl_xor(san, off, 64);
        sad += __shfl_xor(sad, off, 64);
      }
      float pd = sqrtf(sap), nd = sqrtf(san), dd = sqrtf(sad);
      qsum += fmaxf(pd - nd + 1.0f, 0.f) + fmaxf(pd - dd + 2.0f, 0.f);
      qcnt += 1;
    }
  }
  if (lane == 0) { qs[wid] = qsum; qc[wid] = qcnt; }
  __syncthreads();
  if (tid == 0) {
    double tq = (double)qs[0] + qs[1] + qs[2] + qs[3];
    int tqc = qc[0] + qc[1] + qc[2] + qc[3];
    double ce   = rce[0] / (double)max(rvc[0], 1);
    double ctx  = (rpc[0] > 0) ? rctx[0] / (double)rpc[0] : 0.0;
    double quad = (tqc > 0) ? tq / (double)tqc : 0.0;
    out[0] = (float)(ce + 0.5 * quad + 0.1 * ctx);
  }
}

extern "C" void kernel_launch(void* const* d_in, const int* in_sizes, int n_in,
                              void* d_out, int out_size, void* d_ws, size_t ws_size,
                              hipStream_t stream) {
  const float* emb    = (const float*)d_in[0];
  const float* cw     = (const float*)d_in[1];
  const float* cb     = (const float*)d_in[2];
  const int*   labels = (const int*)d_in[3];
  const int*   mask   = (const int*)d_in[4];
  WS* ws = (WS*)d_ws;
  float* out = (float*)d_out;

  k_main <<<NBLK, TPB, 0, stream>>>(emb, cw, cb, labels, mask, ws);
  k_final<<<1, 256, 0, stream>>>(emb, ws, out);
}